// Round 3
// baseline (3269.457 us; speedup 1.0000x reference)
//
#include <hip/hip_runtime.h>
#include <math.h>

#define F_IN   500
#define H_DIM  64
#define C_DIM  40
#define K_STEPS 10
#define ALPHA  0.1f

// ---------------------------------------------------------------------------
// MLP: h0 = relu(x@W1+b1)@W2+b2.  One wave per row.
// Layer1: lane j accumulates hidden col j (W1 loads coalesced, x broadcast).
// Layer2: wave-private LDS broadcast of the 64 hidden values; lanes 0..39
// produce the 40 output channels. No __syncthreads needed (intra-wave LDS).
// ---------------------------------------------------------------------------
__global__ __launch_bounds__(256) void mlp_kernel(
    const float* __restrict__ x, const float* __restrict__ W1,
    const float* __restrict__ b1, const float* __restrict__ W2,
    const float* __restrict__ b2, float* __restrict__ h0,
    float* __restrict__ hA, int N)
{
    __shared__ float lds_h1[256];
    const int wave = threadIdx.x >> 6;
    const int lane = threadIdx.x & 63;
    const int row  = blockIdx.x * 4 + wave;
    if (row >= N) return;

    const float* xr = x + (long long)row * F_IN;
    float acc0 = 0.f, acc1 = 0.f;
    #pragma unroll 4
    for (int k = 0; k < F_IN; k += 2) {
        acc0 += xr[k]     * W1[(k)     * H_DIM + lane];
        acc1 += xr[k + 1] * W1[(k + 1) * H_DIM + lane];
    }
    float h1 = fmaxf(acc0 + acc1 + b1[lane], 0.f);
    lds_h1[wave * 64 + lane] = h1;   // wave-private region; HW waitcnt orders

    if (lane < C_DIM) {
        float o = b2[lane];
        #pragma unroll 8
        for (int j = 0; j < H_DIM; ++j)
            o += lds_h1[wave * 64 + j] * W2[j * C_DIM + lane];
        long long idx = (long long)row * C_DIM + lane;
        h0[idx] = o;
        hA[idx] = o;
    }
}

// ---------------------------------------------------------------------------
// Degree / normalization
// ---------------------------------------------------------------------------
__global__ void deg_init(float* __restrict__ deg, int N) {
    int i = blockIdx.x * 256 + threadIdx.x;
    if (i < N) deg[i] = 1.0f;               // self-loop
}

__global__ void deg_count(const int* __restrict__ dst, float* __restrict__ deg, int E) {
    int e = blockIdx.x * 256 + threadIdx.x;
    if (e < E) atomicAdd(&deg[dst[e]], 1.0f);
}

// in-place deg -> dinv = 1/sqrt(deg); lengths = deg-1 (# in-edges, no loop)
__global__ void dinv_kernel(float* __restrict__ deg, int* __restrict__ lengths, int N) {
    int i = blockIdx.x * 256 + threadIdx.x;
    if (i < N) {
        float d = deg[i];
        deg[i] = 1.0f / sqrtf(d);
        lengths[i] = (int)(d - 0.5f);       // exact: d is integer-valued
    }
}

// ---------------------------------------------------------------------------
// Exclusive prefix scan of row lengths -> row_ptr  (3-kernel block scan)
// ---------------------------------------------------------------------------
__global__ void scan1(const int* __restrict__ len, int* __restrict__ rp,
                      int* __restrict__ bsums, int N) {
    __shared__ int tmp[256];
    int tid = threadIdx.x;
    int gid = blockIdx.x * 256 + tid;
    int v = (gid < N) ? len[gid] : 0;
    tmp[tid] = v;
    __syncthreads();
    for (int off = 1; off < 256; off <<= 1) {
        int t = (tid >= off) ? tmp[tid - off] : 0;
        __syncthreads();
        tmp[tid] += t;
        __syncthreads();
    }
    if (gid < N) rp[gid] = tmp[tid] - v;                 // exclusive
    if (tid == 255) bsums[blockIdx.x] = tmp[tid];        // block total
}

__global__ void scan2(int* __restrict__ bsums, int nb) {
    __shared__ int tmp[512];
    int tid = threadIdx.x;
    int v = (tid < nb) ? bsums[tid] : 0;
    tmp[tid] = v;
    __syncthreads();
    for (int off = 1; off < 512; off <<= 1) {
        int t = (tid >= off) ? tmp[tid - off] : 0;
        __syncthreads();
        tmp[tid] += t;
        __syncthreads();
    }
    if (tid < nb) bsums[tid] = tmp[tid] - v;             // exclusive offsets
}

__global__ void scan3(int* __restrict__ rp, const int* __restrict__ bsums,
                      int* __restrict__ cursor, int N, int E) {
    int gid = blockIdx.x * 256 + threadIdx.x;
    if (gid < N) {
        int v = rp[gid] + bsums[blockIdx.x];
        rp[gid] = v;
        cursor[gid] = v;
    }
    if (gid == 0) rp[N] = E;
}

// ---------------------------------------------------------------------------
// CSR fill: group edge src ids by dst (weights recomputed in prop from dinv)
// ---------------------------------------------------------------------------
__global__ void csr_fill(const int* __restrict__ src,
                         const int* __restrict__ dst,
                         int* __restrict__ cursor,
                         int* __restrict__ esrc, int E) {
    int e = blockIdx.x * 256 + threadIdx.x;
    if (e >= E) return;
    int s = src[e];
    int d = dst[e];
    int pos = atomicAdd(&cursor[d], 1);
    esrc[pos] = s;
}

// ---------------------------------------------------------------------------
// One PPR step:
//   hout[i] = 0.9*dinv[i]^2*hin[i] + 0.1*h0[i] + sum_e 0.9*dinv[i]*dinv[s]*hin[s]
// One wave per node; lanes 0..39 = channels; edge ids + dinv[s] batch-loaded
// by all 64 lanes then broadcast via shuffle.
// ---------------------------------------------------------------------------
__global__ __launch_bounds__(256) void prop_kernel(
    const float* __restrict__ hin, const float* __restrict__ h0,
    const float* __restrict__ dinv, const int* __restrict__ rp,
    const int* __restrict__ esrc,
    float* __restrict__ hout, int N)
{
    const int wave = threadIdx.x >> 6;
    const int lane = threadIdx.x & 63;
    const int row  = blockIdx.x * 4 + wave;
    if (row >= N) return;

    const int rs = rp[row];
    const int re = rp[row + 1];
    const float dr     = dinv[row];
    const float factor = (1.0f - ALPHA) * dr;          // 0.9*dinv[row]
    const int col = (lane < C_DIM) ? lane : (C_DIM - 1);  // lanes>=40 dummies

    long long oidx = (long long)row * C_DIM + col;
    float acc = factor * dr * hin[oidx] + ALPHA * h0[oidx];

    for (int base = rs; base < re; base += 64) {
        int e = base + lane;
        int s = 0; float w = 0.f;
        if (e < re) { s = esrc[e]; w = dinv[s]; }
        int cnt = re - base; if (cnt > 64) cnt = 64;
        for (int t = 0; t < cnt; ++t) {
            int   ss = __shfl(s, t);
            float ww = __shfl(w, t);
            acc = fmaf(factor * ww, hin[(long long)ss * C_DIM + col], acc);
        }
    }
    if (lane < C_DIM) hout[(long long)row * C_DIM + lane] = acc;
}

// ---------------------------------------------------------------------------
// Row-wise log_softmax over 40 channels (wave per row, butterfly reduce)
// ---------------------------------------------------------------------------
__global__ __launch_bounds__(256) void lsm_kernel(const float* __restrict__ hin,
                                                  float* __restrict__ out, int N) {
    const int wave = threadIdx.x >> 6;
    const int lane = threadIdx.x & 63;
    const int row  = blockIdx.x * 4 + wave;
    if (row >= N) return;

    float v = (lane < C_DIM) ? hin[(long long)row * C_DIM + lane] : -INFINITY;
    float m = v;
    for (int off = 32; off; off >>= 1) m = fmaxf(m, __shfl_xor(m, off));
    float e = (lane < C_DIM) ? expf(v - m) : 0.f;
    float s = e;
    for (int off = 32; off; off >>= 1) s += __shfl_xor(s, off);
    if (lane < C_DIM) out[(long long)row * C_DIM + lane] = (v - m) - logf(s);
}

// ---------------------------------------------------------------------------
extern "C" void kernel_launch(void* const* d_in, const int* in_sizes, int n_in,
                              void* d_out, int out_size, void* d_ws, size_t ws_size,
                              hipStream_t stream) {
    const float* x  = (const float*)d_in[0];
    const float* W1 = (const float*)d_in[1];
    const float* b1 = (const float*)d_in[2];
    const float* W2 = (const float*)d_in[3];
    const float* b2 = (const float*)d_in[4];
    // Harness delivers integer inputs as int32 (see contract), NOT int64.
    const int* ei = (const int*)d_in[5];

    const int N = in_sizes[0] / F_IN;          // 100000
    const int E = in_sizes[5] / 2;             // 3200000
    const int* src = ei;
    const int* dst = ei + E;
    float* out = (float*)d_out;

    // workspace carve-up (~46 MB total; d_out doubles as ping-pong buffer)
    char* w = (char*)d_ws;
    float* h0    = (float*)w;  w += (size_t)N * C_DIM * 4;   // 16 MB
    float* hA    = (float*)w;  w += (size_t)N * C_DIM * 4;   // 16 MB
    float* dinv  = (float*)w;  w += (size_t)N * 4;           // deg -> dinv in place
    int*   rp    = (int*)w;    w += (size_t)(N + 1) * 4;
    int*   cursor= (int*)w;    w += (size_t)N * 4;
    int*   bsums = (int*)w;    w += (size_t)512 * 4;
    int*   esrc  = (int*)w;    w += (size_t)E * 4;           // 12.8 MB

    const int nbN = (N + 255) / 256;        // 391
    const int nbE = (E + 255) / 256;
    const int nbRow = (N + 3) / 4;          // wave-per-row kernels

    mlp_kernel<<<nbRow, 256, 0, stream>>>(x, W1, b1, W2, b2, h0, hA, N);

    deg_init <<<nbN, 256, 0, stream>>>(dinv, N);
    deg_count<<<nbE, 256, 0, stream>>>(dst, dinv, E);
    dinv_kernel<<<nbN, 256, 0, stream>>>(dinv, cursor, N);

    scan1<<<nbN, 256, 0, stream>>>(cursor, rp, bsums, N);
    scan2<<<1, 512, 0, stream>>>(bsums, nbN);
    scan3<<<nbN, 256, 0, stream>>>(rp, bsums, cursor, N, E);

    csr_fill<<<nbE, 256, 0, stream>>>(src, dst, cursor, esrc, E);

    // ping-pong: hA <-> out; after 10 steps result is back in hA
    float* a = hA; float* b = out;
    for (int k = 0; k < K_STEPS; ++k) {
        prop_kernel<<<nbRow, 256, 0, stream>>>(a, h0, dinv, rp, esrc, b, N);
        float* t = a; a = b; b = t;
    }

    lsm_kernel<<<nbRow, 256, 0, stream>>>(a, out, N);
}

// Round 4
// 2605.548 us; speedup vs baseline: 1.2548x; 1.2548x over previous
//
#include <hip/hip_runtime.h>
#include <math.h>

#define F_IN   500
#define H_DIM  64
#define C_DIM  40
#define K_STEPS 10
#define ALPHA  0.1f

// ---------------------------------------------------------------------------
// Fused MLP GEMM: h0 = relu(x@W1+b1)@W2+b2, one 64-row tile per block.
// Layer1: classic LDS-tiled fp32 GEMM, K-tile=64, 4x4 register tile/thread.
//   xs: x-tile transposed [k][row], LDA 68 (float4-aligned, low bank alias)
//   ws: W1-tile [k][hcol],  LDA 68
// Layer2: h1 (64x64) round-trips through LDS (reusing xs), W2 LDS-resident.
// ---------------------------------------------------------------------------
#define LDA1 68
__global__ __launch_bounds__(256) void mlp_gemm(
    const float* __restrict__ x, const float* __restrict__ W1,
    const float* __restrict__ b1, const float* __restrict__ W2,
    const float* __restrict__ b2, float* __restrict__ h0,
    float* __restrict__ hA, int N)
{
    __shared__ float smem[64 * LDA1 * 2 + H_DIM * C_DIM];
    float* xs  = smem;                 // 64*68 floats (later reused as h1s)
    float* ws  = smem + 64 * LDA1;     // 64*68
    float* w2s = smem + 2 * 64 * LDA1; // 64*40

    const int t    = threadIdx.x;
    const int row0 = blockIdx.x * 64;
    const int tx   = t & 15;           // hidden-col group (4 cols)
    const int ty   = t >> 4;           // row group (4 rows)

    // W2 -> LDS (read in epilogue, after multiple barriers)
    for (int i = t; i < H_DIM * C_DIM; i += 256) w2s[i] = W2[i];

    const float4 b1v = *(const float4*)&b1[tx * 4];

    float acc[4][4];
    #pragma unroll
    for (int i = 0; i < 4; ++i)
        #pragma unroll
        for (int j = 0; j < 4; ++j) acc[i][j] = 0.f;

    for (int k0 = 0; k0 < F_IN; k0 += 64) {
        __syncthreads();   // previous tile's compute done before overwrite
        // x tile: 64 rows x 64 k, loaded as float4, stored transposed [k][row]
        #pragma unroll
        for (int i = 0; i < 4; ++i) {
            int f  = t + i * 256;          // 0..1023 float4 slots
            int r  = f >> 4;               // tile row 0..63
            int c4 = (f & 15) << 2;        // k offset 0..60
            int grow = row0 + r, gk = k0 + c4;
            float4 v = make_float4(0.f, 0.f, 0.f, 0.f);
            if (grow < N && gk < F_IN)
                v = *(const float4*)&x[(long long)grow * F_IN + gk];
            xs[(c4 + 0) * LDA1 + r] = v.x;
            xs[(c4 + 1) * LDA1 + r] = v.y;
            xs[(c4 + 2) * LDA1 + r] = v.z;
            xs[(c4 + 3) * LDA1 + r] = v.w;
        }
        // W1 tile: 64 k x 64 hcol, natural layout
        #pragma unroll
        for (int i = 0; i < 4; ++i) {
            int f  = t + i * 256;
            int r  = f >> 4;               // k within tile
            int c4 = (f & 15) << 2;        // hcol
            int gk = k0 + r;
            float4 v = make_float4(0.f, 0.f, 0.f, 0.f);
            if (gk < F_IN)
                v = *(const float4*)&W1[(long long)gk * H_DIM + c4];
            *(float4*)&ws[r * LDA1 + c4] = v;
        }
        __syncthreads();
        #pragma unroll 8
        for (int kk = 0; kk < 64; ++kk) {
            float4 a4 = *(const float4*)&xs[kk * LDA1 + ty * 4];
            float4 b4 = *(const float4*)&ws[kk * LDA1 + tx * 4];
            const float av[4] = {a4.x, a4.y, a4.z, a4.w};
            const float bv[4] = {b4.x, b4.y, b4.z, b4.w};
            #pragma unroll
            for (int i = 0; i < 4; ++i)
                #pragma unroll
                for (int j = 0; j < 4; ++j)
                    acc[i][j] = fmaf(av[i], bv[j], acc[i][j]);
        }
    }

    // relu + bias -> h1 in LDS (reuse xs region), layout [row][hcol] LDA 68
    __syncthreads();
    #pragma unroll
    for (int i = 0; i < 4; ++i) {
        float4 hv;
        hv.x = fmaxf(acc[i][0] + b1v.x, 0.f);
        hv.y = fmaxf(acc[i][1] + b1v.y, 0.f);
        hv.z = fmaxf(acc[i][2] + b1v.z, 0.f);
        hv.w = fmaxf(acc[i][3] + b1v.w, 0.f);
        *(float4*)&xs[(ty * 4 + i) * LDA1 + tx * 4] = hv;
    }
    __syncthreads();

    // layer 2: 64 rows x 40 cols = 2560 outputs, 10 per thread
    for (int o = t; o < 64 * C_DIM; o += 256) {
        int r = o / C_DIM;
        int c = o - r * C_DIM;
        float s = b2[c];
        #pragma unroll 16
        for (int j = 0; j < H_DIM; ++j)
            s = fmaf(xs[r * LDA1 + j], w2s[j * C_DIM + c], s);
        int grow = row0 + r;
        if (grow < N) {
            long long idx = (long long)grow * C_DIM + c;
            h0[idx] = s;
            hA[idx] = s;
        }
    }
}

// ---------------------------------------------------------------------------
// Degree / normalization
// ---------------------------------------------------------------------------
__global__ void deg_init(float* __restrict__ deg, int N) {
    int i = blockIdx.x * 256 + threadIdx.x;
    if (i < N) deg[i] = 1.0f;               // self-loop
}

__global__ void deg_count(const int* __restrict__ dst, float* __restrict__ deg, int E) {
    int e = blockIdx.x * 256 + threadIdx.x;
    if (e < E) atomicAdd(&deg[dst[e]], 1.0f);
}

// in-place deg -> dinv = 1/sqrt(deg); lengths = deg-1 (# in-edges, no loop)
__global__ void dinv_kernel(float* __restrict__ deg, int* __restrict__ lengths, int N) {
    int i = blockIdx.x * 256 + threadIdx.x;
    if (i < N) {
        float d = deg[i];
        deg[i] = 1.0f / sqrtf(d);
        lengths[i] = (int)(d - 0.5f);       // exact: d is integer-valued
    }
}

// ---------------------------------------------------------------------------
// Exclusive prefix scan of row lengths -> row_ptr  (3-kernel block scan)
// ---------------------------------------------------------------------------
__global__ void scan1(const int* __restrict__ len, int* __restrict__ rp,
                      int* __restrict__ bsums, int N) {
    __shared__ int tmp[256];
    int tid = threadIdx.x;
    int gid = blockIdx.x * 256 + tid;
    int v = (gid < N) ? len[gid] : 0;
    tmp[tid] = v;
    __syncthreads();
    for (int off = 1; off < 256; off <<= 1) {
        int t = (tid >= off) ? tmp[tid - off] : 0;
        __syncthreads();
        tmp[tid] += t;
        __syncthreads();
    }
    if (gid < N) rp[gid] = tmp[tid] - v;                 // exclusive
    if (tid == 255) bsums[blockIdx.x] = tmp[tid];        // block total
}

__global__ void scan2(int* __restrict__ bsums, int nb) {
    __shared__ int tmp[512];
    int tid = threadIdx.x;
    int v = (tid < nb) ? bsums[tid] : 0;
    tmp[tid] = v;
    __syncthreads();
    for (int off = 1; off < 512; off <<= 1) {
        int t = (tid >= off) ? tmp[tid - off] : 0;
        __syncthreads();
        tmp[tid] += t;
        __syncthreads();
    }
    if (tid < nb) bsums[tid] = tmp[tid] - v;             // exclusive offsets
}

__global__ void scan3(int* __restrict__ rp, const int* __restrict__ bsums,
                      int* __restrict__ cursor, int N, int E) {
    int gid = blockIdx.x * 256 + threadIdx.x;
    if (gid < N) {
        int v = rp[gid] + bsums[blockIdx.x];
        rp[gid] = v;
        cursor[gid] = v;
    }
    if (gid == 0) rp[N] = E;
}

// ---------------------------------------------------------------------------
// CSR fill: group edge src ids by dst (weights recomputed in prop from dinv)
// ---------------------------------------------------------------------------
__global__ void csr_fill(const int* __restrict__ src,
                         const int* __restrict__ dst,
                         int* __restrict__ cursor,
                         int* __restrict__ esrc, int E) {
    int e = blockIdx.x * 256 + threadIdx.x;
    if (e >= E) return;
    int s = src[e];
    int d = dst[e];
    int pos = atomicAdd(&cursor[d], 1);
    esrc[pos] = s;
}

// ---------------------------------------------------------------------------
// One PPR step:
//   hout[i] = 0.9*dinv[i]^2*hin[i] + 0.1*h0[i] + sum_e 0.9*dinv[i]*dinv[s]*hin[s]
// One wave per node; lanes 0..39 = channels; edge ids + dinv[s] batch-loaded
// by all 64 lanes then broadcast via shuffle.
// ---------------------------------------------------------------------------
__global__ __launch_bounds__(256) void prop_kernel(
    const float* __restrict__ hin, const float* __restrict__ h0,
    const float* __restrict__ dinv, const int* __restrict__ rp,
    const int* __restrict__ esrc,
    float* __restrict__ hout, int N)
{
    const int wave = threadIdx.x >> 6;
    const int lane = threadIdx.x & 63;
    const int row  = blockIdx.x * 4 + wave;
    if (row >= N) return;

    const int rs = rp[row];
    const int re = rp[row + 1];
    const float dr     = dinv[row];
    const float factor = (1.0f - ALPHA) * dr;          // 0.9*dinv[row]
    const int col = (lane < C_DIM) ? lane : (C_DIM - 1);  // lanes>=40 dummies

    long long oidx = (long long)row * C_DIM + col;
    float acc = factor * dr * hin[oidx] + ALPHA * h0[oidx];

    for (int base = rs; base < re; base += 64) {
        int e = base + lane;
        int s = 0; float w = 0.f;
        if (e < re) { s = esrc[e]; w = dinv[s]; }
        int cnt = re - base; if (cnt > 64) cnt = 64;
        for (int t = 0; t < cnt; ++t) {
            int   ss = __shfl(s, t);
            float ww = __shfl(w, t);
            acc = fmaf(factor * ww, hin[(long long)ss * C_DIM + col], acc);
        }
    }
    if (lane < C_DIM) hout[(long long)row * C_DIM + lane] = acc;
}

// ---------------------------------------------------------------------------
// Row-wise log_softmax over 40 channels (wave per row, butterfly reduce)
// ---------------------------------------------------------------------------
__global__ __launch_bounds__(256) void lsm_kernel(const float* __restrict__ hin,
                                                  float* __restrict__ out, int N) {
    const int wave = threadIdx.x >> 6;
    const int lane = threadIdx.x & 63;
    const int row  = blockIdx.x * 4 + wave;
    if (row >= N) return;

    float v = (lane < C_DIM) ? hin[(long long)row * C_DIM + lane] : -INFINITY;
    float m = v;
    for (int off = 32; off; off >>= 1) m = fmaxf(m, __shfl_xor(m, off));
    float e = (lane < C_DIM) ? expf(v - m) : 0.f;
    float s = e;
    for (int off = 32; off; off >>= 1) s += __shfl_xor(s, off);
    if (lane < C_DIM) out[(long long)row * C_DIM + lane] = (v - m) - logf(s);
}

// ---------------------------------------------------------------------------
extern "C" void kernel_launch(void* const* d_in, const int* in_sizes, int n_in,
                              void* d_out, int out_size, void* d_ws, size_t ws_size,
                              hipStream_t stream) {
    const float* x  = (const float*)d_in[0];
    const float* W1 = (const float*)d_in[1];
    const float* b1 = (const float*)d_in[2];
    const float* W2 = (const float*)d_in[3];
    const float* b2 = (const float*)d_in[4];
    const int* ei = (const int*)d_in[5];   // int32 per harness contract

    const int N = in_sizes[0] / F_IN;          // 100000
    const int E = in_sizes[5] / 2;             // 3200000
    const int* src = ei;
    const int* dst = ei + E;
    float* out = (float*)d_out;

    // workspace carve-up (~46 MB total; d_out doubles as ping-pong buffer)
    char* w = (char*)d_ws;
    float* h0    = (float*)w;  w += (size_t)N * C_DIM * 4;   // 16 MB
    float* hA    = (float*)w;  w += (size_t)N * C_DIM * 4;   // 16 MB
    float* dinv  = (float*)w;  w += (size_t)N * 4;           // deg -> dinv in place
    int*   rp    = (int*)w;    w += (size_t)(N + 1) * 4;
    int*   cursor= (int*)w;    w += (size_t)N * 4;
    int*   bsums = (int*)w;    w += (size_t)512 * 4;
    int*   esrc  = (int*)w;    w += (size_t)E * 4;           // 12.8 MB

    const int nbN = (N + 255) / 256;        // 391
    const int nbE = (E + 255) / 256;
    const int nbRow = (N + 3) / 4;          // wave-per-row kernels
    const int nbGemm = (N + 63) / 64;       // 1563

    mlp_gemm<<<nbGemm, 256, 0, stream>>>(x, W1, b1, W2, b2, h0, hA, N);

    deg_init <<<nbN, 256, 0, stream>>>(dinv, N);
    deg_count<<<nbE, 256, 0, stream>>>(dst, dinv, E);
    dinv_kernel<<<nbN, 256, 0, stream>>>(dinv, cursor, N);

    scan1<<<nbN, 256, 0, stream>>>(cursor, rp, bsums, N);
    scan2<<<1, 512, 0, stream>>>(bsums, nbN);
    scan3<<<nbN, 256, 0, stream>>>(rp, bsums, cursor, N, E);

    csr_fill<<<nbE, 256, 0, stream>>>(src, dst, cursor, esrc, E);

    // ping-pong: hA <-> out; after 10 steps result is back in hA
    float* a = hA; float* b = out;
    for (int k = 0; k < K_STEPS; ++k) {
        prop_kernel<<<nbRow, 256, 0, stream>>>(a, h0, dinv, rp, esrc, b, N);
        float* t = a; a = b; b = t;
    }

    lsm_kernel<<<nbRow, 256, 0, stream>>>(a, out, N);
}

// Round 5
// 1857.392 us; speedup vs baseline: 1.7602x; 1.4028x over previous
//
#include <hip/hip_runtime.h>
#include <math.h>

#define F_IN   500
#define H_DIM  64
#define C_DIM  40
#define K_STEPS 10
#define ALPHA  0.1f

// ---------------------------------------------------------------------------
// Fused MLP GEMM: h0 = relu(x@W1+b1)@W2+b2, one 64-row tile per block.
// ---------------------------------------------------------------------------
#define LDA1 68
__global__ __launch_bounds__(256) void mlp_gemm(
    const float* __restrict__ x, const float* __restrict__ W1,
    const float* __restrict__ b1, const float* __restrict__ W2,
    const float* __restrict__ b2, float* __restrict__ h0,
    float* __restrict__ hA, int N)
{
    __shared__ float smem[64 * LDA1 * 2 + H_DIM * C_DIM];
    float* xs  = smem;                 // 64*68 floats (later reused as h1s)
    float* ws  = smem + 64 * LDA1;     // 64*68
    float* w2s = smem + 2 * 64 * LDA1; // 64*40

    const int t    = threadIdx.x;
    const int row0 = blockIdx.x * 64;
    const int tx   = t & 15;           // hidden-col group (4 cols)
    const int ty   = t >> 4;           // row group (4 rows)

    for (int i = t; i < H_DIM * C_DIM; i += 256) w2s[i] = W2[i];

    const float4 b1v = *(const float4*)&b1[tx * 4];

    float acc[4][4];
    #pragma unroll
    for (int i = 0; i < 4; ++i)
        #pragma unroll
        for (int j = 0; j < 4; ++j) acc[i][j] = 0.f;

    for (int k0 = 0; k0 < F_IN; k0 += 64) {
        __syncthreads();
        #pragma unroll
        for (int i = 0; i < 4; ++i) {
            int f  = t + i * 256;
            int r  = f >> 4;
            int c4 = (f & 15) << 2;
            int grow = row0 + r, gk = k0 + c4;
            float4 v = make_float4(0.f, 0.f, 0.f, 0.f);
            if (grow < N && gk < F_IN)
                v = *(const float4*)&x[(long long)grow * F_IN + gk];
            xs[(c4 + 0) * LDA1 + r] = v.x;
            xs[(c4 + 1) * LDA1 + r] = v.y;
            xs[(c4 + 2) * LDA1 + r] = v.z;
            xs[(c4 + 3) * LDA1 + r] = v.w;
        }
        #pragma unroll
        for (int i = 0; i < 4; ++i) {
            int f  = t + i * 256;
            int r  = f >> 4;
            int c4 = (f & 15) << 2;
            int gk = k0 + r;
            float4 v = make_float4(0.f, 0.f, 0.f, 0.f);
            if (gk < F_IN)
                v = *(const float4*)&W1[(long long)gk * H_DIM + c4];
            *(float4*)&ws[r * LDA1 + c4] = v;
        }
        __syncthreads();
        #pragma unroll 8
        for (int kk = 0; kk < 64; ++kk) {
            float4 a4 = *(const float4*)&xs[kk * LDA1 + ty * 4];
            float4 b4 = *(const float4*)&ws[kk * LDA1 + tx * 4];
            const float av[4] = {a4.x, a4.y, a4.z, a4.w};
            const float bv[4] = {b4.x, b4.y, b4.z, b4.w};
            #pragma unroll
            for (int i = 0; i < 4; ++i)
                #pragma unroll
                for (int j = 0; j < 4; ++j)
                    acc[i][j] = fmaf(av[i], bv[j], acc[i][j]);
        }
    }

    __syncthreads();
    #pragma unroll
    for (int i = 0; i < 4; ++i) {
        float4 hv;
        hv.x = fmaxf(acc[i][0] + b1v.x, 0.f);
        hv.y = fmaxf(acc[i][1] + b1v.y, 0.f);
        hv.z = fmaxf(acc[i][2] + b1v.z, 0.f);
        hv.w = fmaxf(acc[i][3] + b1v.w, 0.f);
        *(float4*)&xs[(ty * 4 + i) * LDA1 + tx * 4] = hv;
    }
    __syncthreads();

    for (int o = t; o < 64 * C_DIM; o += 256) {
        int r = o / C_DIM;
        int c = o - r * C_DIM;
        float s = b2[c];
        #pragma unroll 16
        for (int j = 0; j < H_DIM; ++j)
            s = fmaf(xs[r * LDA1 + j], w2s[j * C_DIM + c], s);
        int grow = row0 + r;
        if (grow < N) {
            long long idx = (long long)grow * C_DIM + c;
            h0[idx] = s;
            hA[idx] = s;
        }
    }
}

// ---------------------------------------------------------------------------
// Degree / normalization
// ---------------------------------------------------------------------------
__global__ void deg_init(float* __restrict__ deg, int N) {
    int i = blockIdx.x * 256 + threadIdx.x;
    if (i < N) deg[i] = 1.0f;               // self-loop
}

__global__ void deg_count(const int* __restrict__ dst, float* __restrict__ deg, int E) {
    int e = blockIdx.x * 256 + threadIdx.x;
    if (e < E) atomicAdd(&deg[dst[e]], 1.0f);
}

__global__ void dinv_kernel(float* __restrict__ deg, int* __restrict__ lengths, int N) {
    int i = blockIdx.x * 256 + threadIdx.x;
    if (i < N) {
        float d = deg[i];
        deg[i] = 1.0f / sqrtf(d);
        lengths[i] = (int)(d - 0.5f);       // deg-1, exact (integer-valued)
    }
}

// ---------------------------------------------------------------------------
// Exclusive prefix scan of row lengths -> row_ptr  (3-kernel block scan)
// ---------------------------------------------------------------------------
__global__ void scan1(const int* __restrict__ len, int* __restrict__ rp,
                      int* __restrict__ bsums, int N) {
    __shared__ int tmp[256];
    int tid = threadIdx.x;
    int gid = blockIdx.x * 256 + tid;
    int v = (gid < N) ? len[gid] : 0;
    tmp[tid] = v;
    __syncthreads();
    for (int off = 1; off < 256; off <<= 1) {
        int t = (tid >= off) ? tmp[tid - off] : 0;
        __syncthreads();
        tmp[tid] += t;
        __syncthreads();
    }
    if (gid < N) rp[gid] = tmp[tid] - v;
    if (tid == 255) bsums[blockIdx.x] = tmp[tid];
}

__global__ void scan2(int* __restrict__ bsums, int nb) {
    __shared__ int tmp[512];
    int tid = threadIdx.x;
    int v = (tid < nb) ? bsums[tid] : 0;
    tmp[tid] = v;
    __syncthreads();
    for (int off = 1; off < 512; off <<= 1) {
        int t = (tid >= off) ? tmp[tid - off] : 0;
        __syncthreads();
        tmp[tid] += t;
        __syncthreads();
    }
    if (tid < nb) bsums[tid] = tmp[tid] - v;
}

__global__ void scan3(int* __restrict__ rp, const int* __restrict__ bsums,
                      int* __restrict__ cursor, int N, int E) {
    int gid = blockIdx.x * 256 + threadIdx.x;
    if (gid < N) {
        int v = rp[gid] + bsums[blockIdx.x];
        rp[gid] = v;
        cursor[gid] = v;
    }
    if (gid == 0) rp[N] = E;
}

// ---------------------------------------------------------------------------
// CSR fill: group edge src ids by dst
// ---------------------------------------------------------------------------
__global__ void csr_fill(const int* __restrict__ src,
                         const int* __restrict__ dst,
                         int* __restrict__ cursor,
                         int* __restrict__ esrc, int E) {
    int e = blockIdx.x * 256 + threadIdx.x;
    if (e >= E) return;
    int s = src[e];
    int d = dst[e];
    int pos = atomicAdd(&cursor[d], 1);
    esrc[pos] = s;
}

// ---------------------------------------------------------------------------
// PPR step v2: float4 gathers, 4 edge-groups x 16 lanes, 4 independent
// accumulators (MLP=4), one butterfly reduction per row.
//   hout[i] = 0.9*dinv[i]*(dinv[i]*hin[i] + sum_e dinv[s]*hin[s]) + 0.1*h0[i]
// ---------------------------------------------------------------------------
__global__ __launch_bounds__(256) void prop_kernel(
    const float* __restrict__ hin, const float* __restrict__ h0,
    const float* __restrict__ dinv, const int* __restrict__ rp,
    const int* __restrict__ esrc,
    float* __restrict__ hout, int N)
{
    const int wave = threadIdx.x >> 6;
    const int lane = threadIdx.x & 63;
    const int row  = blockIdx.x * 4 + wave;
    if (row >= N) return;

    const int rs = rp[row];
    const int re = rp[row + 1];
    const float dr     = dinv[row];
    const float factor = (1.0f - ALPHA) * dr;       // 0.9*dinv[row]
    const int e4 = lane >> 4;                        // edge subgroup 0..3
    const int q  = lane & 15;                        // chan-quad id
    const int qc = (q < 10) ? q : 9;                 // clamp (lanes q>=10 dummy)

    float4 acc = make_float4(0.f, 0.f, 0.f, 0.f);

    for (int base = rs; base < re; base += 64) {
        // batch-load up to 64 edge ids + weights (one per lane)
        int ee = base + lane;
        int s = 0; float ww = 0.f;
        if (ee < re) { s = esrc[ee]; ww = dinv[s]; }
        int cnt = re - base; if (cnt > 64) cnt = 64;
        // 4 edges per iteration; group e4 handles edge i+e4
        for (int i = 0; i < cnt; i += 4) {
            int t = i + e4;                          // <= 63 always
            int   ss = __shfl(s, t);                 // 0 for padded lanes
            float w  = __shfl(ww, t);                // 0 for padded lanes
            const float4 v = *(const float4*)&hin[(long long)ss * C_DIM + qc * 4];
            acc.x = fmaf(w, v.x, acc.x);
            acc.y = fmaf(w, v.y, acc.y);
            acc.z = fmaf(w, v.z, acc.z);
            acc.w = fmaf(w, v.w, acc.w);
        }
    }

    // reduce the 4 edge-subgroup accumulators (lane bits 4,5)
    acc.x += __shfl_xor(acc.x, 16);
    acc.y += __shfl_xor(acc.y, 16);
    acc.z += __shfl_xor(acc.z, 16);
    acc.w += __shfl_xor(acc.w, 16);
    acc.x += __shfl_xor(acc.x, 32);
    acc.y += __shfl_xor(acc.y, 32);
    acc.z += __shfl_xor(acc.z, 32);
    acc.w += __shfl_xor(acc.w, 32);

    if (lane < 10) {
        const long long rbase = (long long)row * C_DIM + lane * 4;
        const float4 hv  = *(const float4*)&hin[rbase];
        const float4 h0v = *(const float4*)&h0[rbase];
        float4 o;
        o.x = fmaf(factor, acc.x + dr * hv.x, ALPHA * h0v.x);
        o.y = fmaf(factor, acc.y + dr * hv.y, ALPHA * h0v.y);
        o.z = fmaf(factor, acc.z + dr * hv.z, ALPHA * h0v.z);
        o.w = fmaf(factor, acc.w + dr * hv.w, ALPHA * h0v.w);
        *(float4*)&hout[rbase] = o;
    }
}

// ---------------------------------------------------------------------------
// Row-wise log_softmax over 40 channels (wave per row, butterfly reduce)
// ---------------------------------------------------------------------------
__global__ __launch_bounds__(256) void lsm_kernel(const float* __restrict__ hin,
                                                  float* __restrict__ out, int N) {
    const int wave = threadIdx.x >> 6;
    const int lane = threadIdx.x & 63;
    const int row  = blockIdx.x * 4 + wave;
    if (row >= N) return;

    float v = (lane < C_DIM) ? hin[(long long)row * C_DIM + lane] : -INFINITY;
    float m = v;
    for (int off = 32; off; off >>= 1) m = fmaxf(m, __shfl_xor(m, off));
    float e = (lane < C_DIM) ? expf(v - m) : 0.f;
    float s = e;
    for (int off = 32; off; off >>= 1) s += __shfl_xor(s, off);
    if (lane < C_DIM) out[(long long)row * C_DIM + lane] = (v - m) - logf(s);
}

// ---------------------------------------------------------------------------
extern "C" void kernel_launch(void* const* d_in, const int* in_sizes, int n_in,
                              void* d_out, int out_size, void* d_ws, size_t ws_size,
                              hipStream_t stream) {
    const float* x  = (const float*)d_in[0];
    const float* W1 = (const float*)d_in[1];
    const float* b1 = (const float*)d_in[2];
    const float* W2 = (const float*)d_in[3];
    const float* b2 = (const float*)d_in[4];
    const int* ei = (const int*)d_in[5];   // int32 per harness contract

    const int N = in_sizes[0] / F_IN;          // 100000
    const int E = in_sizes[5] / 2;             // 3200000
    const int* src = ei;
    const int* dst = ei + E;
    float* out = (float*)d_out;

    char* w = (char*)d_ws;
    float* h0    = (float*)w;  w += (size_t)N * C_DIM * 4;   // 16 MB
    float* hA    = (float*)w;  w += (size_t)N * C_DIM * 4;   // 16 MB
    float* dinv  = (float*)w;  w += (size_t)N * 4;
    int*   rp    = (int*)w;    w += (size_t)(N + 1) * 4;
    int*   cursor= (int*)w;    w += (size_t)N * 4;
    int*   bsums = (int*)w;    w += (size_t)512 * 4;
    int*   esrc  = (int*)w;    w += (size_t)E * 4;           // 12.8 MB

    const int nbN = (N + 255) / 256;
    const int nbE = (E + 255) / 256;
    const int nbRow = (N + 3) / 4;
    const int nbGemm = (N + 63) / 64;

    mlp_gemm<<<nbGemm, 256, 0, stream>>>(x, W1, b1, W2, b2, h0, hA, N);

    deg_init <<<nbN, 256, 0, stream>>>(dinv, N);
    deg_count<<<nbE, 256, 0, stream>>>(dst, dinv, E);
    dinv_kernel<<<nbN, 256, 0, stream>>>(dinv, cursor, N);

    scan1<<<nbN, 256, 0, stream>>>(cursor, rp, bsums, N);
    scan2<<<1, 512, 0, stream>>>(bsums, nbN);
    scan3<<<nbN, 256, 0, stream>>>(rp, bsums, cursor, N, E);

    csr_fill<<<nbE, 256, 0, stream>>>(src, dst, cursor, esrc, E);

    // ping-pong: hA <-> out; after 10 steps result is back in hA
    float* a = hA; float* b = out;
    for (int k = 0; k < K_STEPS; ++k) {
        prop_kernel<<<nbRow, 256, 0, stream>>>(a, h0, dinv, rp, esrc, b, N);
        float* t = a; a = b; b = t;
    }

    lsm_kernel<<<nbRow, 256, 0, stream>>>(a, out, N);
}